// Round 5
// baseline (132.869 us; speedup 1.0000x reference)
//
#include <hip/hip_runtime.h>
#include <cstdint>

#define Bq 16
#define Nq 512
#define Dq 12
#define HID 32
#define HEADS 4
#define Cq 8
#define LOG2E 1.44269504088896f

// ws layout (float offsets)
#define OFF_G     0u         // [b][n][32]       262144
#define OFF_AS    262144u    // [b][n][4]         32768  (pre-scaled by log2e)
#define OFF_AD    294912u    // [b][n][4]         32768  (pre-scaled by log2e)
#define OFF_TIT   327680u    // [b][h][n]        262144  (ti, h-major)
#define OFF_TJBT  589824u    // [b][n][h]        262144  (tj+b1, n-major)
#define OFF_PACK  851968u    // u32 maskT [b][j][16]  (bit beta of word w = adj[16*beta+w][j])

// ---- k0: per-node h, g, a_s, a_d. 8 nodes/block. ----
__global__ __launch_bounds__(256) void k0_node(
    const float* __restrict__ x, const float* __restrict__ Wp, const float* __restrict__ bp,
    const float* __restrict__ Wg, const float* __restrict__ att_src,
    const float* __restrict__ att_dst, float* __restrict__ ws) {
    __shared__ float xs[8 * Dq];
    __shared__ float hs[8][HID];
    int n_sub = threadIdx.x >> 5;
    int k = threadIdx.x & 31;
    int node0 = blockIdx.x * 8;
    if (threadIdx.x < 8 * Dq) xs[threadIdx.x] = x[(size_t)node0 * Dq + threadIdx.x];
    __syncthreads();
    float s = bp[k];
#pragma unroll
    for (int d = 0; d < Dq; d++) s = fmaf(Wp[k * Dq + d], xs[n_sub * Dq + d], s);
    hs[n_sub][k] = s > 0.f ? s : 0.f;
    __syncthreads();
    float g = 0.f;
#pragma unroll
    for (int d = 0; d < HID; d++) g = fmaf(Wg[k * HID + d], hs[n_sub][d], g);
    int nid = node0 + n_sub;
    ws[OFF_G + (size_t)nid * HID + k] = g;
    float ss = g * att_src[k];   // k = h*8+c
    float sd = g * att_dst[k];
#pragma unroll
    for (int off = 1; off < 8; off <<= 1) {
        ss += __shfl_xor(ss, off);
        sd += __shfl_xor(sd, off);
    }
    if ((k & 7) == 0) {
        int h = k >> 3;
        // pre-scale by log2e so k1 uses a bare v_exp_f32 (exp2)
        ws[OFF_AS + (size_t)nid * HEADS + h] = ss * LOG2E;
        ws[OFF_AD + (size_t)nid * HEADS + h] = sd * LOG2E;
    }
}

// ---- k1_fused: softmax-aggregate + W1 epilogue, 2-j register blocking. ----
// grid (32, Bq), block 256. jl2 = t&7 owns j0+jl2 and j0+jl2+8; ig = t>>3 (i ≡ ig mod 32).
// Every G/as LDS read now feeds TWO j's -> LDS instrs per thread halved (288 -> 144).
__global__ __launch_bounds__(256, 2) void k1_fused(
    const int* __restrict__ adj, const float* __restrict__ bias_g,
    const float* __restrict__ W1, const float* __restrict__ b1,
    float* __restrict__ ws) {
    int b = blockIdx.y;
    int j0 = blockIdx.x * 16;
    int t = threadIdx.x;
    int jl2 = t & 7;
    int ig = t >> 3;          // 0..31
    int par = ig >> 4;        // mask bit parity

    __shared__ float smem[6688];
    // main: gs0 @0 (2304), gs1 @2304 (2304), as0 @4608 (256), as1 @4864 (256)
    // epilogue union [0,6176): red @0 (2880), hgs @2880 (576), W1s @3456 (2176), tjs @5632 (544)
    // mskp @6176 (512 u32) -- disjoint from everything
    float* red = smem;
    float* hgs = smem + 2880;
    float* W1s = smem + 3456;
    float* tjs = smem + 5632;
    uint32_t* mskp = (uint32_t*)(smem + 6176);   // [par][jl][w]

    float4 adv0 = *(const float4*)(ws + OFF_AD + ((size_t)b * Nq + j0 + jl2) * HEADS);
    float4 adv1 = *(const float4*)(ws + OFF_AD + ((size_t)b * Nq + j0 + jl2 + 8) * HEADS);

    const float* Gb = ws + OFF_G + (size_t)b * Nq * HID;
    const float* Ab = ws + OFF_AS + (size_t)b * Nq * HEADS;
    int ii_s = t >> 2, q_s = t & 3;   // staging coords

    float4 ga, gb2;
    float av;
    {   // chunk 0: load + write LDS before first barrier
        const float* src = Gb + (size_t)ii_s * HID + q_s * 8;
        ga = *(const float4*)src;
        gb2 = *(const float4*)(src + 4);
        av = Ab[t];
        *(float4*)&smem[ii_s * 36 + q_s * 8] = ga;
        *(float4*)&smem[ii_s * 36 + q_s * 8 + 4] = gb2;
        smem[4608 + t] = av;
    }
    const int* adjp = adj + ((size_t)b * Nq + ig) * Nq + j0 + jl2;
    int cur[2][2], nxt[2][2];
#pragma unroll
    for (int mi = 0; mi < 2; mi++)
#pragma unroll
        for (int js = 0; js < 2; js++) cur[mi][js] = adjp[(size_t)(32 * mi) * Nq + 8 * js];

    float lsum[2][HEADS] = {};
    float acc[2][HEADS][Cq] = {};
    uint32_t mask0 = 0, mask1 = 0;

    for (int c = 0; c < 8; c++) {
        __syncthreads();
        const float* gsc = (c & 1) ? smem + 2304 : smem;
        const float* asc = (c & 1) ? smem + 4864 : smem + 4608;
        if (c < 7) {                     // T14: issue next-chunk loads EARLY
            const float* src = Gb + (size_t)((c + 1) * 64 + ii_s) * HID + q_s * 8;
            ga = *(const float4*)src;
            gb2 = *(const float4*)(src + 4);
            av = Ab[(c + 1) * 256 + t];
#pragma unroll
            for (int mi = 0; mi < 2; mi++)
#pragma unroll
                for (int js = 0; js < 2; js++)
                    nxt[mi][js] = adjp[(size_t)(64 * (c + 1) + 32 * mi) * Nq + 8 * js];
        }
#pragma unroll
        for (int mi = 0; mi < 2; mi++) {
            int m = 2 * c + mi;
            int i = 32 * m + ig;
            int ii = ig + 32 * mi;
            bool c0 = (cur[mi][0] != 0), c1 = (cur[mi][1] != 0);
            mask0 |= (uint32_t)c0 << (2 * m + par);
            mask1 |= (uint32_t)c1 << (2 * m + par);
            bool m0 = c0 || (i == j0 + jl2);
            bool m1 = c1 || (i == j0 + jl2 + 8);
            float4 asv = *(const float4*)&asc[ii * 4];
            const float* gr = &gsc[ii * 36];
#pragma unroll
            for (int h = 0; h < HEADS; h++) {
                float as_h = (h == 0) ? asv.x : (h == 1) ? asv.y : (h == 2) ? asv.z : asv.w;
                float ad0 = (h == 0) ? adv0.x : (h == 1) ? adv0.y : (h == 2) ? adv0.z : adv0.w;
                float ad1 = (h == 0) ? adv1.x : (h == 1) ? adv1.y : (h == 2) ? adv1.z : adv1.w;
                float z0 = as_h + ad0, z1 = as_h + ad1;
                float l0 = fmaxf(z0, 0.2f * z0), l1 = fmaxf(z1, 0.2f * z1);
                float e0 = m0 ? __builtin_amdgcn_exp2f(l0) : 0.f;
                float e1 = m1 ? __builtin_amdgcn_exp2f(l1) : 0.f;
                lsum[0][h] += e0;
                lsum[1][h] += e1;
                float4 g0 = *(const float4*)(gr + h * 8);
                float4 g1 = *(const float4*)(gr + h * 8 + 4);
                acc[0][h][0] = fmaf(e0, g0.x, acc[0][h][0]);
                acc[0][h][1] = fmaf(e0, g0.y, acc[0][h][1]);
                acc[0][h][2] = fmaf(e0, g0.z, acc[0][h][2]);
                acc[0][h][3] = fmaf(e0, g0.w, acc[0][h][3]);
                acc[0][h][4] = fmaf(e0, g1.x, acc[0][h][4]);
                acc[0][h][5] = fmaf(e0, g1.y, acc[0][h][5]);
                acc[0][h][6] = fmaf(e0, g1.z, acc[0][h][6]);
                acc[0][h][7] = fmaf(e0, g1.w, acc[0][h][7]);
                acc[1][h][0] = fmaf(e1, g0.x, acc[1][h][0]);
                acc[1][h][1] = fmaf(e1, g0.y, acc[1][h][1]);
                acc[1][h][2] = fmaf(e1, g0.z, acc[1][h][2]);
                acc[1][h][3] = fmaf(e1, g0.w, acc[1][h][3]);
                acc[1][h][4] = fmaf(e1, g1.x, acc[1][h][4]);
                acc[1][h][5] = fmaf(e1, g1.y, acc[1][h][5]);
                acc[1][h][6] = fmaf(e1, g1.z, acc[1][h][6]);
                acc[1][h][7] = fmaf(e1, g1.w, acc[1][h][7]);
            }
        }
        if (c < 7) {                     // T14: ds_write LATE
            float* gsn = (c & 1) ? smem : smem + 2304;
            float* asn = (c & 1) ? smem + 4608 : smem + 4864;
            *(float4*)&gsn[ii_s * 36 + q_s * 8] = ga;
            *(float4*)&gsn[ii_s * 36 + q_s * 8 + 4] = gb2;
            asn[t] = av;
#pragma unroll
            for (int mi = 0; mi < 2; mi++)
#pragma unroll
                for (int js = 0; js < 2; js++) cur[mi][js] = nxt[mi][js];
        }
    }

    // mask partials: [par][jl][w], w = ig&15; bit (2m+par) of word w = adj[32m+16par+w][j]
    // matches k3 format: i = 16*beta + w with beta = 2m+par.
    mskp[par * 256 + jl2 * 16 + (ig & 15)] = mask0;
    mskp[par * 256 + (jl2 + 8) * 16 + (ig & 15)] = mask1;

    __syncthreads();   // main-loop LDS dead; epilogue union usable

    {   // combine mask halves + store (one word per thread, coalesced)
        int jl = t >> 4, w = t & 15;
        uint32_t word = mskp[jl * 16 + w] | mskp[256 + jl * 16 + w];
        ((uint32_t*)(ws + OFF_PACK))[((size_t)b * Nq + j0 + jl) * 16 + w] = word;
    }
    {   // stage W1 (row pad 64 -> 68)
        const float4* src = (const float4*)W1;  // 512 float4
        for (int k = t; k < 512; k += 256) {
            int h = k >> 4, q = k & 15;
            *(float4*)&W1s[h * 68 + q * 4] = src[k];
        }
    }
    // reduce over ig: shfl over ig bits 0..2 (lane strides 8,16,32), LDS over 4 waves
    int w = t >> 6;
    auto dump = [&](int r, float v) {
        v += __shfl_xor(v, 8);
        v += __shfl_xor(v, 16);
        v += __shfl_xor(v, 32);
        if ((t & 63) < 8) red[(r * 8 + jl2) * 5 + w] = v;
    };
#pragma unroll
    for (int js = 0; js < 2; js++)
#pragma unroll
        for (int h = 0; h < HEADS; h++) dump(js * 36 + h, lsum[js][h]);
#pragma unroll
    for (int js = 0; js < 2; js++)
#pragma unroll
        for (int h = 0; h < HEADS; h++)
#pragma unroll
            for (int cc = 0; cc < Cq; cc++) dump(js * 36 + 4 + h * 8 + cc, acc[js][h][cc]);
    __syncthreads();
    for (int o = t; o < 576; o += 256) {  // 72 r × 8 jl2 totals over 4 waves
        float* pp = &red[o * 5];
        pp[4] = (pp[0] + pp[1]) + (pp[2] + pp[3]);
    }
    __syncthreads();
    for (int o = t; o < 512; o += 256) {  // hg = acc/lsum + bias_g
        int d = o >> 4, jl = o & 15;
        int js = jl >> 3, j2 = jl & 7;
        float s = red[((js * 36 + 4 + d) * 8 + j2) * 5 + 4];
        float l = red[((js * 36 + (d >> 3)) * 8 + j2) * 5 + 4];
        hgs[jl * 36 + d] = s * __builtin_amdgcn_rcpf(l) + bias_g[d];
    }
    __syncthreads();
    {   // W1 epilogue: thread (jl = t&15, tg = t>>4) computes h = tg, tg+16
        int jl = t & 15, tg = t >> 4;
        int j = j0 + jl;
        float si0 = 0.f, sj0 = 0.f, si1 = 0.f, sj1 = 0.f;
        const float* w0 = &W1s[tg * 68];
        const float* w1 = &W1s[(tg + 16) * 68];
        const float* hr = &hgs[jl * 36];
#pragma unroll
        for (int d = 0; d < HID; d++) {
            float hv = hr[d];
            si0 = fmaf(hv, w0[d], si0);
            sj0 = fmaf(hv, w0[32 + d], sj0);
            si1 = fmaf(hv, w1[d], si1);
            sj1 = fmaf(hv, w1[32 + d], sj1);
        }
        ws[OFF_TIT + ((size_t)b * HID + tg) * Nq + j] = si0;
        ws[OFF_TIT + ((size_t)b * HID + tg + 16) * Nq + j] = si1;
        tjs[tg * 17 + jl] = sj0 + b1[tg];
        tjs[(tg + 16) * 17 + jl] = sj1 + b1[tg + 16];
    }
    __syncthreads();
    for (int o = t; o < 512; o += 256) {   // coalesced transposed store [b][n][h]
        int jj = o >> 5, h = o & 31;
        ws[OFF_TJBT + ((size_t)b * Nq + j0 + jj) * HID + h] = tjs[h * 17 + jj];
    }
}

// ---- k3: pairwise score, 2-j blocking, scalarized w2/b2, fully unrolled. ----
__global__ __launch_bounds__(256) void k3_score(const float* __restrict__ w2_p,
                                                const float* __restrict__ b2_p,
                                                const float* __restrict__ ws,
                                                float* __restrict__ out) {
    int b = blockIdx.y;
    int i0 = blockIdx.x * 16;
    int j = threadIdx.x;        // jA = j, jB = j + 256
    __shared__ float tisT[16 * 36];  // [ii][h]
    {
        int h = threadIdx.x >> 4, ii = threadIdx.x & 15;
        tisT[ii * 36 + h] = ws[OFF_TIT + ((size_t)b * HID + h) * Nq + i0 + ii];
        tisT[ii * 36 + h + 16] = ws[OFF_TIT + ((size_t)b * HID + h + 16) * Nq + i0 + ii];
    }
    float4 ta[8], tb[8];
    const float* rA = ws + OFF_TJBT + ((size_t)b * Nq + j) * HID;
    const float* rB = rA + (size_t)256 * HID;
#pragma unroll
    for (int q = 0; q < 8; q++) {
        ta[q] = *(const float4*)(rA + q * 4);
        tb[q] = *(const float4*)(rB + q * 4);
    }
    // w2/b2 are block-uniform: pin to SGPRs, freeing ~33 VGPRs
    float w2l[HID];
#pragma unroll
    for (int h = 0; h < HID; h++)
        w2l[h] = __int_as_float(__builtin_amdgcn_readfirstlane(__float_as_int(w2_p[h])));
    float b2 = __int_as_float(__builtin_amdgcn_readfirstlane(__float_as_int(b2_p[0])));
    const uint32_t* mrow = (const uint32_t*)(ws + OFF_PACK) + ((size_t)b * Nq + j) * 16;
    uint4 mAv[4], mBv[4];
#pragma unroll
    for (int q = 0; q < 4; q++) {
        mAv[q] = ((const uint4*)mrow)[q];
        mBv[q] = ((const uint4*)(mrow + 256 * 16))[q];
    }
    int bit = i0 >> 4;
    __syncthreads();
#pragma unroll
    for (int ii = 0; ii < 16; ii++) {
        int i = i0 + ii;
        uint32_t mA = (ii & 3) == 0 ? mAv[ii >> 2].x : (ii & 3) == 1 ? mAv[ii >> 2].y
                    : (ii & 3) == 2 ? mAv[ii >> 2].z : mAv[ii >> 2].w;
        uint32_t mB = (ii & 3) == 0 ? mBv[ii >> 2].x : (ii & 3) == 1 ? mBv[ii >> 2].y
                    : (ii & 3) == 2 ? mBv[ii >> 2].z : mBv[ii >> 2].w;
        bool onA = (((mA >> bit) & 1u) != 0) && (i != j);
        bool onB = (((mB >> bit) & 1u) != 0) && (i != j + 256);
        float sA = b2, sB = b2;
#pragma unroll
        for (int q = 0; q < 8; q++) {
            float4 tq = *(const float4*)&tisT[ii * 36 + q * 4];  // broadcast b128
#pragma unroll
            for (int e = 0; e < 4; e++) {
                float ti = (e == 0) ? tq.x : (e == 1) ? tq.y : (e == 2) ? tq.z : tq.w;
                float tjA = (e == 0) ? ta[q].x : (e == 1) ? ta[q].y : (e == 2) ? ta[q].z : ta[q].w;
                float tjB = (e == 0) ? tb[q].x : (e == 1) ? tb[q].y : (e == 2) ? tb[q].z : tb[q].w;
                float tA = ti + tjA;
                tA = tA > 0.f ? tA : 0.f;
                sA = fmaf(tA, w2l[q * 4 + e], sA);
                float tB = ti + tjB;
                tB = tB > 0.f ? tB : 0.f;
                sB = fmaf(tB, w2l[q * 4 + e], sB);
            }
        }
        float scA = __builtin_amdgcn_rcpf(1.f + __expf(-sA));
        float scB = __builtin_amdgcn_rcpf(1.f + __expf(-sB));
        out[((size_t)b * Nq + i) * Nq + j] = onA ? scA : 0.f;
        out[((size_t)b * Nq + i) * Nq + j + 256] = onB ? scB : 0.f;
    }
}

extern "C" void kernel_launch(void* const* d_in, const int* in_sizes, int n_in,
                              void* d_out, int out_size, void* d_ws, size_t ws_size,
                              hipStream_t stream) {
    const float* x       = (const float*)d_in[0];
    const int*   adj     = (const int*)d_in[1];
    const float* Wp      = (const float*)d_in[2];
    const float* bp      = (const float*)d_in[3];
    const float* Wg      = (const float*)d_in[4];
    const float* att_src = (const float*)d_in[5];
    const float* att_dst = (const float*)d_in[6];
    const float* bias_g  = (const float*)d_in[7];
    const float* W1      = (const float*)d_in[8];
    const float* b1      = (const float*)d_in[9];
    const float* w2      = (const float*)d_in[10];
    const float* b2      = (const float*)d_in[11];
    float* out = (float*)d_out;
    float* ws = (float*)d_ws;
    (void)in_sizes; (void)n_in; (void)out_size; (void)ws_size;

    k0_node<<<dim3(1024), dim3(256), 0, stream>>>(x, Wp, bp, Wg, att_src, att_dst, ws);
    k1_fused<<<dim3(Nq / 16, Bq), dim3(256), 0, stream>>>(adj, bias_g, W1, b1, ws);
    k3_score<<<dim3(32, Bq), dim3(256), 0, stream>>>(w2, b2, ws, out);
}